// Round 17
// baseline (81.574 us; speedup 1.0000x reference)
//
#include <hip/hip_runtime.h>

// Conv2D 3x3 VALID NHWC, B=16 H=W=224 C=32 F=32 -> [16,222,222,32] fp32.
// Round 17: R16 failed because it THINNED the per-row compute (2 chunks) and
// had a 518/512 tail. Keep R14's 64-col row work (4 chunks, 36 MFMA/row),
// gain waves/SIMD instead via:
//  - ring-3 (SWRITE(r+3) hits slot r%3 AFTER compute(r) consumed row r;
//    in-wave DS order + sched_barrier make it safe) -> 12.7 KB/wave
//  - 4-wave blocks: 50.7 KB/block -> 3 blocks/CU (152 KB exact LDS fit)
//    = 12 waves/CU = 3 waves/SIMD (+50% TLP vs R14)
//  - RPW=3 strips: 74 x 3 = 222 exact; 4736 waves = 1184 blocks = 8 x 148
//    (clean m204 XCD remap, fine-grained balancing, no lockstep tail).
// Vertical halo 1.67x is L2/L3-served (R13/R14: FETCH stays near-ideal).

#define HO 222
#define WO 222
#define HIN 224
#define WIN 224
#define CIN 32
#define FOUT 32

#define RPW 3                 // output rows per wave-strip (74 x 3 = 222)
#define WROWB 4224            // 66 px * 64 B bf16 (conflict-free layout)
#define WAVELDS (3 * WROWB)   // ring-3: 12672 B/wave
#define NSG 9                 // stage granule-iters (528/64 -> 9, clamped)

typedef __attribute__((ext_vector_type(8))) short short8;
typedef __attribute__((ext_vector_type(4))) float float4v;

__device__ inline short f2bf(float f) {                  // RNE (weights only)
    unsigned u = __builtin_bit_cast(unsigned, f);
    unsigned r = (u + 0x7FFFu + ((u >> 16) & 1u)) >> 16;
    return (short)r;
}

__global__ __launch_bounds__(256, 3) void conv3x3_wave(
    const float* __restrict__ x,     // [16,224,224,32]
    const float* __restrict__ w,     // [32][288 = (kh,kw,c)]
    const float* __restrict__ bias,  // [32]
    float* __restrict__ out)         // [16,222,222,32]
{
    __shared__ uint4 lds_all[4 * WAVELDS / 16];          // 50688 B -> 3 blocks/CU
    const int tid  = threadIdx.x;
    const int lane = tid & 63;
    const int wave = tid >> 6;                           // 0..3
    char* wbase = reinterpret_cast<char*>(lds_all) + wave * WAVELDS;

    const int fcol = lane & 15;            // A row (filter) / D col (pixel)
    const int kq   = lane >> 4;            // k-slice: channels kq*8..+7

    // ---- weights -> register A-fragments ----
    short8 bfr[2][9];
#pragma unroll
    for (int h = 0; h < 2; ++h) {
        const float* wf = w + (h * 16 + fcol) * 288 + kq * 8;
#pragma unroll
        for (int s = 0; s < 9; ++s) {
            float4 lo = reinterpret_cast<const float4*>(wf + s * 32)[0];
            float4 hi = reinterpret_cast<const float4*>(wf + s * 32)[1];
            short8 v;
            v[0] = f2bf(lo.x); v[1] = f2bf(lo.y); v[2] = f2bf(lo.z); v[3] = f2bf(lo.w);
            v[4] = f2bf(hi.x); v[5] = f2bf(hi.y); v[6] = f2bf(hi.z); v[7] = f2bf(hi.w);
            bfr[h][s] = v;
        }
    }
    const float4 bias0 = reinterpret_cast<const float4*>(bias)[kq];
    const float4 bias1 = reinterpret_cast<const float4*>(bias)[4 + kq];

    // ---- m204 bijective XCD remap: nwg = 1184 = 8 * 148 ----
    const int orig = blockIdx.x;
    const int wid  = (orig & 7) * 148 + (orig >> 3);

    // wave-strip id; rst fastest -> vertical neighbors contiguous on one XCD
    const int W    = wid * 4 + wave;       // 0..4735
    const int b    = W / 296;              // 4 colstrips * 74 rowstrips
    const int rem  = W - b * 296;
    const int cst  = rem / 74;             // 0..3
    const int rst  = rem - cst * 74;       // 0..73
    const int c0   = cst * 64;
    const int gr0  = rst * RPW;            // 0..219; staged rows <= 223 (no clamp)
    const int nck  = (cst < 3) ? 4 : 2;    // cst=3 covers cols 192..221

    float4 sv[NSG];                        // stage registers (const-indexed)

#define SLOAD(RR)                                                             \
    {                                                                         \
        const int ir_ = gr0 + (RR);                                           \
        _Pragma("unroll")                                                     \
        for (int i_ = 0; i_ < NSG; ++i_) {                                    \
            int g_ = lane + 64 * i_; if (g_ > 527) g_ = 527;                  \
            int px_ = g_ >> 3, sub_ = g_ & 7;                                 \
            int ic_ = c0 + px_; if (ic_ > WIN - 1) ic_ = WIN - 1;             \
            sv[i_] = *reinterpret_cast<const float4*>(                        \
                x + ((b * HIN + ir_) * WIN + ic_) * CIN + sub_ * 4);          \
        }                                                                     \
    }

#define SWRITE(SLOT)                                                          \
    {                                                                         \
        char* sb_ = wbase + (SLOT) * WROWB;                                   \
        _Pragma("unroll")                                                     \
        for (int i_ = 0; i_ < NSG; ++i_) {                                    \
            int g_ = lane + 64 * i_; if (g_ > 527) g_ = 527;                  \
            int px_ = g_ >> 3, sub_ = g_ & 7;                                 \
            uint4 u_ = __builtin_bit_cast(uint4, sv[i_]);                     \
            uint2 p_;                                                         \
            p_.x = __builtin_amdgcn_perm(u_.y, u_.x, 0x07060302u);            \
            p_.y = __builtin_amdgcn_perm(u_.w, u_.z, 0x07060302u);            \
            *reinterpret_cast<uint2*>(sb_ + px_ * 64 + sub_ * 8) = p_;        \
        }                                                                     \
    }

    // ---------- prologue: rows 0,1,2 -> slots 0,1,2 ----------
    SLOAD(0); SWRITE(0);
    SLOAD(1); SWRITE(1);
    SLOAD(2); SWRITE(2);

    // ---------- barrier-free main loop (3 rows) ----------
#pragma unroll 1
    for (int r = 0; r < RPW; ++r) {
        if (r < RPW - 1) SLOAD(r + 3);               // rows 3,4 in flight
        __builtin_amdgcn_sched_barrier(0);

        const int ho = gr0 + r;
#pragma unroll
        for (int ck = 0; ck < 4; ++ck) {
            if (ck < nck) {
                float4v acc0 = {0.f, 0.f, 0.f, 0.f};
                float4v acc1 = {0.f, 0.f, 0.f, 0.f};
#pragma unroll
                for (int s = 0; s < 9; ++s) {
                    const int kh = s / 3, kw = s % 3;
                    int slot = r + kh; if (slot >= 3) slot -= 3;
                    const short8 a = *reinterpret_cast<const short8*>(
                        wbase + slot * WROWB + (ck * 16 + fcol + kw) * 64 + kq * 16);
                    acc0 = __builtin_amdgcn_mfma_f32_16x16x32_bf16(bfr[0][s], a, acc0, 0, 0, 0);
                    acc1 = __builtin_amdgcn_mfma_f32_16x16x32_bf16(bfr[1][s], a, acc1, 0, 0, 0);
                }
                // D[filter][pixel]: col(lane&15)=pixel, row=kq*4+r=filter
                const int wo = c0 + ck * 16 + fcol;
                if (wo < WO) {
                    float* o = out + ((b * HO + ho) * WO + wo) * FOUT;
                    float4 v0 = {acc0[0] + bias0.x, acc0[1] + bias0.y,
                                 acc0[2] + bias0.z, acc0[3] + bias0.w};
                    float4 v1 = {acc1[0] + bias1.x, acc1[1] + bias1.y,
                                 acc1[2] + bias1.z, acc1[3] + bias1.w};
                    reinterpret_cast<float4*>(o)[kq]     = v0;
                    reinterpret_cast<float4*>(o)[4 + kq] = v1;
                }
            }
        }

        __builtin_amdgcn_sched_barrier(0);
        // row r+3 -> slot r%3 (row r just fully consumed; in-wave DS order)
        if (r < RPW - 1) { int ws = r; if (ws >= 3) ws -= 3; SWRITE(ws); }
    }
}

extern "C" void kernel_launch(void* const* d_in, const int* in_sizes, int n_in,
                              void* d_out, int out_size, void* d_ws, size_t ws_size,
                              hipStream_t stream) {
    const float* x    = (const float*)d_in[0];
    const float* w    = (const float*)d_in[1];
    const float* bias = (const float*)d_in[2];
    float* out        = (float*)d_out;

    conv3x3_wave<<<dim3(1184), dim3(256), 0, stream>>>(x, w, bias, out);
}

// Round 18
// 57.574 us; speedup vs baseline: 1.4168x; 1.4168x over previous
//
#include <hip/hip_runtime.h>

// Conv2D 3x3 VALID NHWC, B=16 H=W=224 C=32 F=32 -> [16,222,222,32] fp32.
// Round 18: R14 (45.6us best) limited by 2 waves/SIMD (16.9 KB LDS/wave).
// R16 failed (thin 18-MFMA rows + 518/512 tail); R17 failed (256-thr blocks
// hit a VGPR-cap anomaly -> spill). This round stays on the proven
// 512-thr/(512,2) shape and buys TLP via LDS/wave:
//   ring-3 x 48-col strips -> 9.6 KB/wave, block 76.8 KB -> 2 blocks/CU
//   = 16 waves/CU = 4/SIMD (2x R14), compute 27 MFMA/row, grid 370 < 512
//   slots (all co-resident, no tail), sv 36->28 regs (~126 total <= 128).
// Work decode exact: 5 colstrips {48,48,48,48,30}, 37 rowstrips x RPW=6.

#define HO 222
#define WO 222
#define HIN 224
#define WIN 224
#define CIN 32
#define FOUT 32

#define RPW 6                 // output rows per wave-strip (37 x 6 = 222)
#define SPX 50                // staged px per row (48 + 2 halo)
#define WROWB 3200            // 50 px * 64 B bf16
#define WAVELDS (3 * WROWB)   // ring-3: 9600 B/wave -> block 76800 B
#define NSG 7                 // stage granule-iters (400 granules / 64 lanes)

typedef __attribute__((ext_vector_type(8))) short short8;
typedef __attribute__((ext_vector_type(4))) float float4v;

__device__ inline short f2bf(float f) {                  // RNE (weights only)
    unsigned u = __builtin_bit_cast(unsigned, f);
    unsigned r = (u + 0x7FFFu + ((u >> 16) & 1u)) >> 16;
    return (short)r;
}

__global__ __launch_bounds__(512, 2) void conv3x3_wave(
    const float* __restrict__ x,     // [16,224,224,32]
    const float* __restrict__ w,     // [32][288 = (kh,kw,c)]
    const float* __restrict__ bias,  // [32]
    float* __restrict__ out)         // [16,222,222,32]
{
    __shared__ uint4 lds_all[8 * WAVELDS / 16];          // 76800 B -> 2 blocks/CU
    const int tid  = threadIdx.x;
    const int lane = tid & 63;
    const int wave = tid >> 6;                           // 0..7
    char* wbase = reinterpret_cast<char*>(lds_all) + wave * WAVELDS;

    const int fcol = lane & 15;            // A row (filter) / D col (pixel)
    const int kq   = lane >> 4;            // k-slice: channels kq*8..+7

    // ---- weights -> register A-fragments ----
    short8 bfr[2][9];
#pragma unroll
    for (int h = 0; h < 2; ++h) {
        const float* wf = w + (h * 16 + fcol) * 288 + kq * 8;
#pragma unroll
        for (int s = 0; s < 9; ++s) {
            float4 lo = reinterpret_cast<const float4*>(wf + s * 32)[0];
            float4 hi = reinterpret_cast<const float4*>(wf + s * 32)[1];
            short8 v;
            v[0] = f2bf(lo.x); v[1] = f2bf(lo.y); v[2] = f2bf(lo.z); v[3] = f2bf(lo.w);
            v[4] = f2bf(hi.x); v[5] = f2bf(hi.y); v[6] = f2bf(hi.z); v[7] = f2bf(hi.w);
            bfr[h][s] = v;
        }
    }
    const float4 bias0 = reinterpret_cast<const float4*>(bias)[kq];
    const float4 bias1 = reinterpret_cast<const float4*>(bias)[4 + kq];

    // ---- m204 bijective XCD remap: nwg = 370 = 8*46 + 2 ----
    const int orig = blockIdx.x;
    const int xcd  = orig & 7;
    const int wid  = (xcd < 2 ? xcd * 47 : 2 * 47 + (xcd - 2) * 46) + (orig >> 3);

    // wave-strip id; rst fastest -> vertical neighbors contiguous on one XCD
    const int W    = wid * 8 + wave;       // 0..2959
    const int b    = W / 185;              // 5 colstrips * 37 rowstrips
    const int rem  = W - b * 185;
    const int cst  = rem / 37;             // 0..4
    const int rst  = rem - cst * 37;       // 0..36
    const int c0   = cst * 48;
    const int gr0  = rst * RPW;            // 0..216; staged rows <= 223 (no clamp)
    const int nck  = (cst < 4) ? 3 : 2;    // cst=4 covers cols 192..221

    float4 sv[NSG];                        // stage registers (const-indexed)

#define SLOAD(RR)                                                             \
    {                                                                         \
        const int ir_ = gr0 + (RR);                                           \
        _Pragma("unroll")                                                     \
        for (int i_ = 0; i_ < NSG; ++i_) {                                    \
            int g_ = lane + 64 * i_; if (g_ > 399) g_ = 399;                  \
            int px_ = g_ >> 3, sub_ = g_ & 7;                                 \
            int ic_ = c0 + px_; if (ic_ > WIN - 1) ic_ = WIN - 1;             \
            sv[i_] = *reinterpret_cast<const float4*>(                        \
                x + ((b * HIN + ir_) * WIN + ic_) * CIN + sub_ * 4);          \
        }                                                                     \
    }

#define SWRITE(SLOT)                                                          \
    {                                                                         \
        char* sb_ = wbase + (SLOT) * WROWB;                                   \
        _Pragma("unroll")                                                     \
        for (int i_ = 0; i_ < NSG; ++i_) {                                    \
            int g_ = lane + 64 * i_; if (g_ > 399) g_ = 399;                  \
            int px_ = g_ >> 3, sub_ = g_ & 7;                                 \
            uint4 u_ = __builtin_bit_cast(uint4, sv[i_]);                     \
            uint2 p_;                                                         \
            p_.x = __builtin_amdgcn_perm(u_.y, u_.x, 0x07060302u);            \
            p_.y = __builtin_amdgcn_perm(u_.w, u_.z, 0x07060302u);            \
            *reinterpret_cast<uint2*>(sb_ + px_ * 64 + sub_ * 8) = p_;        \
        }                                                                     \
    }

    // ---------- prologue: rows 0,1,2 -> slots 0,1,2 ----------
    SLOAD(0); SWRITE(0);
    SLOAD(1); SWRITE(1);
    SLOAD(2); SWRITE(2);

    // ---------- barrier-free main loop ----------
    int rm = 0;                            // r % 3
#pragma unroll 1
    for (int r = 0; r < RPW; ++r) {
        if (r < RPW - 1) SLOAD(r + 3);               // rows 3..7 in flight
        __builtin_amdgcn_sched_barrier(0);

        const int ho = gr0 + r;
#pragma unroll
        for (int ck = 0; ck < 3; ++ck) {
            if (ck < nck) {
                float4v acc0 = {0.f, 0.f, 0.f, 0.f};
                float4v acc1 = {0.f, 0.f, 0.f, 0.f};
#pragma unroll
                for (int s = 0; s < 9; ++s) {
                    const int kh = s / 3, kw = s % 3;
                    int slot = rm + kh; if (slot >= 3) slot -= 3;
                    const short8 a = *reinterpret_cast<const short8*>(
                        wbase + slot * WROWB + (ck * 16 + fcol + kw) * 64 + kq * 16);
                    acc0 = __builtin_amdgcn_mfma_f32_16x16x32_bf16(bfr[0][s], a, acc0, 0, 0, 0);
                    acc1 = __builtin_amdgcn_mfma_f32_16x16x32_bf16(bfr[1][s], a, acc1, 0, 0, 0);
                }
                // D[filter][pixel]: col(lane&15)=pixel, row=kq*4+r=filter
                const int wo = c0 + ck * 16 + fcol;
                if (wo < WO) {
                    float* o = out + ((b * HO + ho) * WO + wo) * FOUT;
                    float4 v0 = {acc0[0] + bias0.x, acc0[1] + bias0.y,
                                 acc0[2] + bias0.z, acc0[3] + bias0.w};
                    float4 v1 = {acc1[0] + bias1.x, acc1[1] + bias1.y,
                                 acc1[2] + bias1.z, acc1[3] + bias1.w};
                    reinterpret_cast<float4*>(o)[kq]     = v0;
                    reinterpret_cast<float4*>(o)[4 + kq] = v1;
                }
            }
        }

        __builtin_amdgcn_sched_barrier(0);
        // row r+3 -> slot r%3 (row r fully consumed; in-wave DS order)
        if (r < RPW - 1) SWRITE(rm);

        rm += 1; if (rm == 3) rm = 0;
    }
}

extern "C" void kernel_launch(void* const* d_in, const int* in_sizes, int n_in,
                              void* d_out, int out_size, void* d_ws, size_t ws_size,
                              hipStream_t stream) {
    const float* x    = (const float*)d_in[0];
    const float* w    = (const float*)d_in[1];
    const float* bias = (const float*)d_in[2];
    float* out        = (float*)d_out;

    conv3x3_wave<<<dim3(370), dim3(512), 0, stream>>>(x, w, bias, out);
}

// Round 19
// 52.758 us; speedup vs baseline: 1.5462x; 1.0913x over previous
//
#include <hip/hip_runtime.h>

// Conv2D 3x3 VALID NHWC, B=16 H=W=224 C=32 F=32 -> [16,222,222,32] fp32.
// Round 19: R14 (45.6us) limited by 2 waves/SIMD; R18 proved +waves helps
// only if UNIFORM (grid 370 -> 1.45 blocks/CU avg, tail ate the gain).
// This round: exact 2 blocks/CU.
//  - 384-thr blocks (6 waves), 64-col strips (full 36 MFMA/row), ring-3:
//    12.7 KB/wave x 6 = 76.0 KB/block -> 2 blocks/CU = 3 waves/SIMD.
//  - work = 4 colstrips x 48 rowstrips x 16 = 3072 waves = 512 blocks
//    = 8 XCDs x 64 (clean bijective remap, no tail, all co-resident).
//  - row strips 5/4 rows (30x5 + 18x4 = 222 exact); staged rows <= 223
//    -> no row clamp. Ring-3 WAR: SWRITE(r+3)->slot r%3 after compute(r)
//    consumed row r (in-wave DS order; validated in R17/R18 passes).

#define HO 222
#define WO 222
#define HIN 224
#define WIN 224
#define CIN 32
#define FOUT 32

#define WROWB 4224            // 66 px * 64 B bf16 (conflict-free layout)
#define WAVELDS (3 * WROWB)   // ring-3: 12672 B/wave -> block 76032 B
#define NSG 9                 // stage granule-iters (528/64 -> 9, clamped)

typedef __attribute__((ext_vector_type(8))) short short8;
typedef __attribute__((ext_vector_type(4))) float float4v;

__device__ inline short f2bf(float f) {                  // RNE (weights only)
    unsigned u = __builtin_bit_cast(unsigned, f);
    unsigned r = (u + 0x7FFFu + ((u >> 16) & 1u)) >> 16;
    return (short)r;
}

__global__ __launch_bounds__(384, 2) void conv3x3_wave(
    const float* __restrict__ x,     // [16,224,224,32]
    const float* __restrict__ w,     // [32][288 = (kh,kw,c)]
    const float* __restrict__ bias,  // [32]
    float* __restrict__ out)         // [16,222,222,32]
{
    __shared__ uint4 lds_all[6 * WAVELDS / 16];          // 76032 B -> 2 blocks/CU
    const int tid  = threadIdx.x;
    const int lane = tid & 63;
    const int wave = tid >> 6;                           // 0..5
    char* wbase = reinterpret_cast<char*>(lds_all) + wave * WAVELDS;

    const int fcol = lane & 15;            // A row (filter) / D col (pixel)
    const int kq   = lane >> 4;            // k-slice: channels kq*8..+7

    // ---- weights -> register A-fragments ----
    short8 bfr[2][9];
#pragma unroll
    for (int h = 0; h < 2; ++h) {
        const float* wf = w + (h * 16 + fcol) * 288 + kq * 8;
#pragma unroll
        for (int s = 0; s < 9; ++s) {
            float4 lo = reinterpret_cast<const float4*>(wf + s * 32)[0];
            float4 hi = reinterpret_cast<const float4*>(wf + s * 32)[1];
            short8 v;
            v[0] = f2bf(lo.x); v[1] = f2bf(lo.y); v[2] = f2bf(lo.z); v[3] = f2bf(lo.w);
            v[4] = f2bf(hi.x); v[5] = f2bf(hi.y); v[6] = f2bf(hi.z); v[7] = f2bf(hi.w);
            bfr[h][s] = v;
        }
    }
    const float4 bias0 = reinterpret_cast<const float4*>(bias)[kq];
    const float4 bias1 = reinterpret_cast<const float4*>(bias)[4 + kq];

    // ---- bijective XCD remap: nwg = 512 = 8 * 64 ----
    const int orig = blockIdx.x;
    const int wid  = (orig & 7) * 64 + (orig >> 3);

    // wave-strip id; rst fastest -> vertical neighbors contiguous on one XCD
    const int W    = wid * 6 + wave;       // 0..3071
    const int b    = W / 192;              // 4 colstrips * 48 rowstrips
    const int rem  = W - b * 192;
    const int cst  = rem / 48;             // 0..3
    const int rst  = rem - cst * 48;       // 0..47
    const int c0   = cst * 64;
    const int nrows = (rst < 30) ? 5 : 4;  // 30*5 + 18*4 = 222
    const int gr0   = (rst < 30) ? 5 * rst : 150 + 4 * (rst - 30);
    const int nck  = (cst < 3) ? 4 : 2;    // cst=3 covers cols 192..221

    float4 sv[NSG];                        // stage registers (const-indexed)

#define SLOAD(RR)                                                             \
    {                                                                         \
        const int ir_ = gr0 + (RR);       /* <= gr0+nrows+1 <= 223 */         \
        _Pragma("unroll")                                                     \
        for (int i_ = 0; i_ < NSG; ++i_) {                                    \
            int g_ = lane + 64 * i_; if (g_ > 527) g_ = 527;                  \
            int px_ = g_ >> 3, sub_ = g_ & 7;                                 \
            int ic_ = c0 + px_; if (ic_ > WIN - 1) ic_ = WIN - 1;             \
            sv[i_] = *reinterpret_cast<const float4*>(                        \
                x + ((b * HIN + ir_) * WIN + ic_) * CIN + sub_ * 4);          \
        }                                                                     \
    }

#define SWRITE(SLOT)                                                          \
    {                                                                         \
        char* sb_ = wbase + (SLOT) * WROWB;                                   \
        _Pragma("unroll")                                                     \
        for (int i_ = 0; i_ < NSG; ++i_) {                                    \
            int g_ = lane + 64 * i_; if (g_ > 527) g_ = 527;                  \
            int px_ = g_ >> 3, sub_ = g_ & 7;                                 \
            uint4 u_ = __builtin_bit_cast(uint4, sv[i_]);                     \
            uint2 p_;                                                         \
            p_.x = __builtin_amdgcn_perm(u_.y, u_.x, 0x07060302u);            \
            p_.y = __builtin_amdgcn_perm(u_.w, u_.z, 0x07060302u);            \
            *reinterpret_cast<uint2*>(sb_ + px_ * 64 + sub_ * 8) = p_;        \
        }                                                                     \
    }

    // ---------- prologue: rows 0,1,2 -> slots 0,1,2 ----------
    SLOAD(0); SWRITE(0);
    SLOAD(1); SWRITE(1);
    SLOAD(2); SWRITE(2);

    // ---------- barrier-free main loop (nrows = 4 or 5, wave-uniform) ----------
    int rm = 0;                            // r % 3
#pragma unroll 1
    for (int r = 0; r < nrows; ++r) {
        if (r < nrows - 1) SLOAD(r + 3);             // rows 3..nrows+1 in flight
        __builtin_amdgcn_sched_barrier(0);

        const int ho = gr0 + r;                      // < 222 by construction
#pragma unroll
        for (int ck = 0; ck < 4; ++ck) {
            if (ck < nck) {
                float4v acc0 = {0.f, 0.f, 0.f, 0.f};
                float4v acc1 = {0.f, 0.f, 0.f, 0.f};
#pragma unroll
                for (int s = 0; s < 9; ++s) {
                    const int kh = s / 3, kw = s % 3;
                    int slot = rm + kh; if (slot >= 3) slot -= 3;
                    const short8 a = *reinterpret_cast<const short8*>(
                        wbase + slot * WROWB + (ck * 16 + fcol + kw) * 64 + kq * 16);
                    acc0 = __builtin_amdgcn_mfma_f32_16x16x32_bf16(bfr[0][s], a, acc0, 0, 0, 0);
                    acc1 = __builtin_amdgcn_mfma_f32_16x16x32_bf16(bfr[1][s], a, acc1, 0, 0, 0);
                }
                // D[filter][pixel]: col(lane&15)=pixel, row=kq*4+r=filter
                const int wo = c0 + ck * 16 + fcol;
                if (wo < WO) {
                    float* o = out + ((b * HO + ho) * WO + wo) * FOUT;
                    float4 v0 = {acc0[0] + bias0.x, acc0[1] + bias0.y,
                                 acc0[2] + bias0.z, acc0[3] + bias0.w};
                    float4 v1 = {acc1[0] + bias1.x, acc1[1] + bias1.y,
                                 acc1[2] + bias1.z, acc1[3] + bias1.w};
                    reinterpret_cast<float4*>(o)[kq]     = v0;
                    reinterpret_cast<float4*>(o)[4 + kq] = v1;
                }
            }
        }

        __builtin_amdgcn_sched_barrier(0);
        // row r+3 -> slot r%3 (row r fully consumed; in-wave DS order)
        if (r < nrows - 1) SWRITE(rm);

        rm += 1; if (rm == 3) rm = 0;
    }
}

extern "C" void kernel_launch(void* const* d_in, const int* in_sizes, int n_in,
                              void* d_out, int out_size, void* d_ws, size_t ws_size,
                              hipStream_t stream) {
    const float* x    = (const float*)d_in[0];
    const float* w    = (const float*)d_in[1];
    const float* bias = (const float*)d_in[2];
    float* out        = (float*)d_out;

    conv3x3_wave<<<dim3(512), dim3(384), 0, stream>>>(x, w, bias, out);
}